// Round 1
// baseline (412.249 us; speedup 1.0000x reference)
//
#include <hip/hip_runtime.h>
#include <math.h>

#define BB 4
#define NN 2048
#define GG 1024
#define CC 3
#define MM 2049   // NN+1

// ---------------- workspace layout ----------------
struct Ws {
  int   nearest[BB * NN];
  int   best_pred[BB * GG];   // -1 => gt g has no assigned point (exists_g == false)
  int   next_pred[BB * NN];
  int   col_cnt[BB * NN];
  int   keep[BB * NN];        // surviving row for column j (valid when col_cnt>=1)
  int   nmax[BB];
  float cdist_sum[BB];
  float sem_sum[BB];
  float lossf_sum[BB];
  float lossb_sum[BB];
};

// position transform + pairwise distance, bit-matching XLA's sub->mul->add->sqrt
__device__ __forceinline__ float posx(float p) { return __fadd_rn(__fmul_rn(p, 0.15f), -29.925f); }
__device__ __forceinline__ float posy(float p) { return __fadd_rn(__fmul_rn(p, 0.15f), -14.925f); }
__device__ __forceinline__ float pdist(float ax, float ay, float bx, float by) {
  float dx = __fsub_rn(ax, bx);
  float dy = __fsub_rn(ay, by);
  return __fsqrt_rn(__fadd_rn(__fmul_rn(dx, dx), __fmul_rn(dy, dy)));
}

// ---------------- kernels ----------------

__global__ void k_zero(float* __restrict__ out, int n) {
  int n4 = n >> 2;
  float4 z = make_float4(0.f, 0.f, 0.f, 0.f);
  for (int t = blockIdx.x * blockDim.x + threadIdx.x; t < n4; t += gridDim.x * blockDim.x)
    reinterpret_cast<float4*>(out)[t] = z;
  int t = blockIdx.x * blockDim.x + threadIdx.x;
  int tail = n & 3;
  if (t < tail) out[n4 * 4 + t] = 0.f;
}

__global__ void k_init(Ws* ws) {
  int t = blockIdx.x * blockDim.x + threadIdx.x;
  if (t < BB * NN) ws->col_cnt[t] = 0;
  if (t < BB) {
    ws->nmax[t] = 0;
    ws->cdist_sum[t] = 0.f;
    ws->sem_sum[t] = 0.f;
    ws->lossf_sum[t] = 0.f;
    ws->lossb_sum[t] = 0.f;
  }
}

// nearest gt per point, min distance, semantic one-hot, per-batch reductions
__global__ __launch_bounds__(256) void k_nearest(const float* __restrict__ positions,
                                                 const float* __restrict__ gt_pts,
                                                 const int* __restrict__ gt_type,
                                                 const float* __restrict__ semantics,
                                                 Ws* ws, float* __restrict__ out) {
  __shared__ float spts[GG * 2];
  __shared__ float sred[4];
  __shared__ int   sredi[4];
  const int bpb = NN / 256;                 // blocks per batch
  int b = blockIdx.x / bpb;
  int i = (blockIdx.x % bpb) * 256 + threadIdx.x;

  for (int t = threadIdx.x; t < GG * 2; t += 256) spts[t] = gt_pts[b * GG * 2 + t];
  __syncthreads();

  float px = posx(positions[(size_t)(b * NN + i) * 2 + 0]);
  float py = posy(positions[(size_t)(b * NN + i) * 2 + 1]);

  float dmin = INFINITY;
  int gmin = 0;
  for (int g = 0; g < GG; ++g) {
    float d = pdist(px, py, spts[2 * g], spts[2 * g + 1]);
    if (d < dmin) { dmin = d; gmin = g; }    // strict < : first-index tie-break like jnp.argmin
  }
  ws->nearest[b * NN + i] = gmin;

  int cls = gt_type[b * GG + gmin];
  float* sg = out + 3 + (size_t)BB * MM * MM;
  sg[(size_t)b * CC * NN + 0 * NN + i] = (cls == 0) ? 1.f : 0.f;
  sg[(size_t)b * CC * NN + 1 * NN + i] = (cls == 1) ? 1.f : 0.f;
  sg[(size_t)b * CC * NN + 2 * NN + i] = (cls == 2) ? 1.f : 0.f;
  float sem = semantics[(size_t)b * CC * NN + (size_t)cls * NN + i];

  int lane = threadIdx.x & 63, w = threadIdx.x >> 6;

  // sum of min distances
  float v = dmin;
  #pragma unroll
  for (int o = 32; o > 0; o >>= 1) v += __shfl_down(v, o, 64);
  if (lane == 0) sred[w] = v;
  __syncthreads();
  if (threadIdx.x == 0) atomicAdd(&ws->cdist_sum[b], sred[0] + sred[1] + sred[2] + sred[3]);
  __syncthreads();

  // sum of gathered semantics
  v = sem;
  #pragma unroll
  for (int o = 32; o > 0; o >>= 1) v += __shfl_down(v, o, 64);
  if (lane == 0) sred[w] = v;
  __syncthreads();
  if (threadIdx.x == 0) atomicAdd(&ws->sem_sum[b], sred[0] + sred[1] + sred[2] + sred[3]);
  __syncthreads();

  // max nearest index
  int m = gmin;
  #pragma unroll
  for (int o = 32; o > 0; o >>= 1) m = max(m, __shfl_down(m, o, 64));
  if (lane == 0) sredi[w] = m;
  __syncthreads();
  if (threadIdx.x == 0)
    atomicMax(&ws->nmax[b], max(max(sredi[0], sredi[1]), max(sredi[2], sredi[3])));
}

// per gt g: first point (ascending i, strict <) with nearest==g minimizing distance; -1 if none
__global__ __launch_bounds__(256) void k_bestpred(const float* __restrict__ positions,
                                                  const float* __restrict__ gt_pts, Ws* ws) {
  const int bpb = GG / 256;
  int b = blockIdx.x / bpb;
  int g = (blockIdx.x % bpb) * 256 + threadIdx.x;

  float gx = gt_pts[(size_t)(b * GG + g) * 2 + 0];
  float gy = gt_pts[(size_t)(b * GG + g) * 2 + 1];
  const int* nb = ws->nearest + b * NN;
  const float* pb = positions + (size_t)b * NN * 2;

  float dmin = INFINITY;
  int imin = -1;
  for (int i = 0; i < NN; ++i) {
    if (nb[i] == g) {
      float d = pdist(posx(pb[2 * i]), posy(pb[2 * i + 1]), gx, gy);
      if (d < dmin) { dmin = d; imin = i; }
    }
  }
  ws->best_pred[b * GG + g] = imin;
}

// the jax.lax.while_loop walk, replicated literally
__global__ __launch_bounds__(256) void k_walk(const int* __restrict__ gt_ins, Ws* ws) {
  __shared__ int sins[GG];
  __shared__ int sbest[GG];
  const int bpb = NN / 256;
  int b = blockIdx.x / bpb;
  int i = (blockIdx.x % bpb) * 256 + threadIdx.x;

  for (int t = threadIdx.x; t < GG; t += 256) {
    sins[t]  = gt_ins[b * GG + t];
    sbest[t] = ws->best_pred[b * GG + t];
  }
  __syncthreads();

  int nmax = ws->nmax[b];
  int idx = ws->nearest[b * NN + i];
  int steps = 0, res = -1;
  while (true) {
    bool is_end = idx >= nmax;
    int gnr = is_end ? -1 : idx + 1;
    int gn = gnr & (GG - 1);                 // jnp.mod for pow2 (handles -1 -> G-1)
    bool ex = (!is_end) && (sbest[gn] >= 0);
    bool same = sins[idx & (GG - 1)] == sins[gn];
    bool matched = ex && same;
    res = matched ? sbest[gn] : -1;
    bool stop = matched || (!same) || (steps >= GG + 2);
    idx = gnr;
    ++steps;
    if (stop) break;
  }
  ws->next_pred[b * NN + i] = res;
  if (res >= 0) atomicAdd(&ws->col_cnt[b * NN + res], 1);
}

// surviving row per column: argmin over pointing rows of dist_map[i][j] (first-index ties)
__global__ __launch_bounds__(256) void k_keep(const float* __restrict__ positions, Ws* ws) {
  const int bpb = NN / 256;
  int b = blockIdx.x / bpb;
  int j = (blockIdx.x % bpb) * 256 + threadIdx.x;

  int cnt = ws->col_cnt[b * NN + j];
  int kp = -1;
  if (cnt >= 1) {
    const float* pb = positions + (size_t)b * NN * 2;
    float jx = posx(pb[2 * j]);
    float jy = posy(pb[2 * j + 1]);
    const int* np_ = ws->next_pred + b * NN;
    float dmin = INFINITY;
    for (int i = 0; i < NN; ++i) {
      if (np_[i] == j) {
        float d = pdist(posx(pb[2 * i]), posy(pb[2 * i + 1]), jx, jy);
        if (d < dmin) { dmin = d; kp = i; }
      }
    }
  }
  ws->keep[b * NN + j] = kp;
}

// write the 1-entries of A (out already zeroed)
__global__ __launch_bounds__(256) void k_scatter(Ws* ws, float* __restrict__ out) {
  const int bpb = NN / 256;
  int b = blockIdx.x / bpb;
  int i = (blockIdx.x % bpb) * 256 + threadIdx.x;

  float* A = out + 3 + (size_t)b * MM * MM;

  int j = ws->next_pred[b * NN + i];
  bool surv = (j >= 0) && (ws->keep[b * NN + j] == i);
  if (surv) A[(size_t)i * MM + j] = 1.0f;          // row i keeps its match
  else      A[(size_t)i * MM + (MM - 1)] = 1.0f;   // row fix: dustbin column

  if (ws->col_cnt[b * NN + i] == 0)                // i as column index
    A[(size_t)(MM - 1) * MM + i] = 1.0f;           // col fix: dustbin row
}

// loss gathers + per-batch sums (tgt_f / tgt_b derived analytically)
__global__ __launch_bounds__(256) void k_loss(const float* __restrict__ matches, Ws* ws) {
  __shared__ float sred[4];
  const int bpb = NN / 256;
  int b = blockIdx.x / bpb;
  int k = (blockIdx.x % bpb) * 256 + threadIdx.x;

  int j = ws->next_pred[b * NN + k];
  bool surv = (j >= 0) && (ws->keep[b * NN + j] == k);
  int tf = surv ? j : (MM - 1);
  float vf = matches[(size_t)b * MM * MM + (size_t)k * MM + tf];

  int cnt = ws->col_cnt[b * NN + k];
  int tb = (cnt > 0) ? ws->keep[b * NN + k] : (MM - 1);
  float vb = matches[(size_t)b * MM * MM + (size_t)k * MM + tb];

  int lane = threadIdx.x & 63, w = threadIdx.x >> 6;

  float v = vf;
  #pragma unroll
  for (int o = 32; o > 0; o >>= 1) v += __shfl_down(v, o, 64);
  if (lane == 0) sred[w] = v;
  __syncthreads();
  if (threadIdx.x == 0) atomicAdd(&ws->lossf_sum[b], sred[0] + sred[1] + sred[2] + sred[3]);
  __syncthreads();

  v = vb;
  #pragma unroll
  for (int o = 32; o > 0; o >>= 1) v += __shfl_down(v, o, 64);
  if (lane == 0) sred[w] = v;
  __syncthreads();
  if (threadIdx.x == 0) atomicAdd(&ws->lossb_sum[b], sred[0] + sred[1] + sred[2] + sred[3]);
}

__global__ void k_final(Ws* ws, float* __restrict__ out) {
  if (threadIdx.x == 0 && blockIdx.x == 0) {
    float cm = 0.f, ml = 0.f, sl = 0.f;
    for (int b = 0; b < BB; ++b) {
      cm += ws->cdist_sum[b] / (float)NN;
      float lf = -(ws->lossf_sum[b] / (float)(MM - 1));
      float lb = -(ws->lossb_sum[b] / (float)(MM - 1));
      ml += 0.5f * (lf + lb);
      sl += -(ws->sem_sum[b] / (float)NN);
    }
    out[0] = cm / (float)BB;
    out[1] = ml / (float)BB;
    out[2] = sl / (float)BB;
  }
}

// ---------------- launch ----------------
extern "C" void kernel_launch(void* const* d_in, const int* in_sizes, int n_in,
                              void* d_out, int out_size, void* d_ws, size_t ws_size,
                              hipStream_t stream) {
  (void)in_sizes; (void)n_in; (void)ws_size;
  const float* matches   = (const float*)d_in[0];
  const float* positions = (const float*)d_in[1];
  const float* semantics = (const float*)d_in[2];
  // d_in[3] = masks (unused by reference)
  const float* gt_pts    = (const float*)d_in[4];
  const int*   gt_ins    = (const int*)d_in[5];
  const int*   gt_type   = (const int*)d_in[6];
  float* out = (float*)d_out;
  Ws* ws = (Ws*)d_ws;

  k_zero<<<2048, 256, 0, stream>>>(out, out_size);
  k_init<<<(BB * NN + 255) / 256, 256, 0, stream>>>(ws);
  k_nearest<<<BB * (NN / 256), 256, 0, stream>>>(positions, gt_pts, gt_type, semantics, ws, out);
  k_bestpred<<<BB * (GG / 256), 256, 0, stream>>>(positions, gt_pts, ws);
  k_walk<<<BB * (NN / 256), 256, 0, stream>>>(gt_ins, ws);
  k_keep<<<BB * (NN / 256), 256, 0, stream>>>(positions, ws);
  k_scatter<<<BB * (NN / 256), 256, 0, stream>>>(ws, out);
  k_loss<<<BB * (NN / 256), 256, 0, stream>>>(matches, ws);
  k_final<<<1, 64, 0, stream>>>(ws, out);
}

// Round 2
// 171.596 us; speedup vs baseline: 2.4024x; 2.4024x over previous
//
#include <hip/hip_runtime.h>
#include <math.h>

#define BB 4
#define NN 2048
#define GG 1024
#define CC 3
#define MM 2049   // NN+1

typedef unsigned long long u64;
#define KEY_EMPTY 0xFFFFFFFFFFFFFFFFULL

// ---------------- workspace layout ----------------
struct Ws {
  int   nearest[BB * NN];
  u64   best_key[BB * GG];    // (bits(dmin)<<32) | i ; EMPTY => no assigned point
  u64   keep_key[BB * NN];    // (bits(dist)<<32) | i ; surviving row for column j
  int   next_pred[BB * NN];
  int   col_cnt[BB * NN];
  int   nmax[BB];
  float cdist_sum[BB];
  float sem_sum[BB];
  float lossf_sum[BB];
  float lossb_sum[BB];
};

// position transform + pairwise distance, bit-matching XLA's sub->mul->add->sqrt
__device__ __forceinline__ float posx(float p) { return __fadd_rn(__fmul_rn(p, 0.15f), -29.925f); }
__device__ __forceinline__ float posy(float p) { return __fadd_rn(__fmul_rn(p, 0.15f), -14.925f); }
__device__ __forceinline__ float pdist(float ax, float ay, float bx, float by) {
  float dx = __fsub_rn(ax, bx);
  float dy = __fsub_rn(ay, by);
  return __fsqrt_rn(__fadd_rn(__fmul_rn(dx, dx), __fmul_rn(dy, dy)));
}
__device__ __forceinline__ u64 pack_key(float d, int i) {
  return ((u64)__float_as_uint(d) << 32) | (unsigned int)i;
}

// ---------------- kernels ----------------

__global__ void k_zero(float* __restrict__ out, int n) {
  int n4 = n >> 2;
  float4 z = make_float4(0.f, 0.f, 0.f, 0.f);
  for (int t = blockIdx.x * blockDim.x + threadIdx.x; t < n4; t += gridDim.x * blockDim.x)
    reinterpret_cast<float4*>(out)[t] = z;
  int t = blockIdx.x * blockDim.x + threadIdx.x;
  int tail = n & 3;
  if (t < tail) out[n4 * 4 + t] = 0.f;
}

__global__ void k_init(Ws* ws) {
  int t = blockIdx.x * blockDim.x + threadIdx.x;
  if (t < BB * NN) {
    ws->col_cnt[t] = 0;
    ws->keep_key[t] = KEY_EMPTY;
  }
  if (t < BB * GG) ws->best_key[t] = KEY_EMPTY;
  if (t < BB) {
    ws->nmax[t] = 0;
    ws->cdist_sum[t] = 0.f;
    ws->sem_sum[t] = 0.f;
    ws->lossf_sum[t] = 0.f;
    ws->lossb_sum[t] = 0.f;
  }
}

// nearest gt per point, min distance, semantic one-hot, per-batch reductions,
// and scatter-argmin for best_pred_g (cd[i,nearest[i]] == dmin[i])
__global__ __launch_bounds__(256) void k_nearest(const float* __restrict__ positions,
                                                 const float* __restrict__ gt_pts,
                                                 const int* __restrict__ gt_type,
                                                 const float* __restrict__ semantics,
                                                 Ws* ws, float* __restrict__ out) {
  __shared__ float spts[GG * 2];
  __shared__ float sred[4];
  __shared__ int   sredi[4];
  const int bpb = NN / 256;                 // blocks per batch
  int b = blockIdx.x / bpb;
  int i = (blockIdx.x % bpb) * 256 + threadIdx.x;

  for (int t = threadIdx.x; t < GG * 2; t += 256) spts[t] = gt_pts[b * GG * 2 + t];
  __syncthreads();

  float px = posx(positions[(size_t)(b * NN + i) * 2 + 0]);
  float py = posy(positions[(size_t)(b * NN + i) * 2 + 1]);

  float dmin = INFINITY;
  int gmin = 0;
  #pragma unroll 4
  for (int g = 0; g < GG; ++g) {
    float d = pdist(px, py, spts[2 * g], spts[2 * g + 1]);
    if (d < dmin) { dmin = d; gmin = g; }    // strict < : first-index tie-break like jnp.argmin
  }
  ws->nearest[b * NN + i] = gmin;
  atomicMin(&ws->best_key[b * GG + gmin], pack_key(dmin, i));

  int cls = gt_type[b * GG + gmin];
  float* sg = out + 3 + (size_t)BB * MM * MM;
  sg[(size_t)b * CC * NN + 0 * NN + i] = (cls == 0) ? 1.f : 0.f;
  sg[(size_t)b * CC * NN + 1 * NN + i] = (cls == 1) ? 1.f : 0.f;
  sg[(size_t)b * CC * NN + 2 * NN + i] = (cls == 2) ? 1.f : 0.f;
  float sem = semantics[(size_t)b * CC * NN + (size_t)cls * NN + i];

  int lane = threadIdx.x & 63, w = threadIdx.x >> 6;

  // sum of min distances
  float v = dmin;
  #pragma unroll
  for (int o = 32; o > 0; o >>= 1) v += __shfl_down(v, o, 64);
  if (lane == 0) sred[w] = v;
  __syncthreads();
  if (threadIdx.x == 0) atomicAdd(&ws->cdist_sum[b], sred[0] + sred[1] + sred[2] + sred[3]);
  __syncthreads();

  // sum of gathered semantics
  v = sem;
  #pragma unroll
  for (int o = 32; o > 0; o >>= 1) v += __shfl_down(v, o, 64);
  if (lane == 0) sred[w] = v;
  __syncthreads();
  if (threadIdx.x == 0) atomicAdd(&ws->sem_sum[b], sred[0] + sred[1] + sred[2] + sred[3]);
  __syncthreads();

  // max nearest index
  int m = gmin;
  #pragma unroll
  for (int o = 32; o > 0; o >>= 1) m = max(m, __shfl_down(m, o, 64));
  if (lane == 0) sredi[w] = m;
  __syncthreads();
  if (threadIdx.x == 0)
    atomicMax(&ws->nmax[b], max(max(sredi[0], sredi[1]), max(sredi[2], sredi[3])));
}

// the jax.lax.while_loop walk + scatter-argmin for keep[]
__global__ __launch_bounds__(256) void k_walk(const int* __restrict__ gt_ins,
                                              const float* __restrict__ positions, Ws* ws) {
  __shared__ int sins[GG];
  __shared__ int sbest[GG];
  const int bpb = NN / 256;
  int b = blockIdx.x / bpb;
  int i = (blockIdx.x % bpb) * 256 + threadIdx.x;

  for (int t = threadIdx.x; t < GG; t += 256) {
    sins[t] = gt_ins[b * GG + t];
    u64 k = ws->best_key[b * GG + t];
    sbest[t] = (k == KEY_EMPTY) ? -1 : (int)(k & 0xFFFFFFFFULL);
  }
  __syncthreads();

  int nmax = ws->nmax[b];
  int idx = ws->nearest[b * NN + i];
  int steps = 0, res = -1;
  while (true) {
    bool is_end = idx >= nmax;
    int gnr = is_end ? -1 : idx + 1;
    int gn = gnr & (GG - 1);                 // jnp.mod for pow2 (handles -1 -> G-1)
    bool ex = (!is_end) && (sbest[gn] >= 0);
    bool same = sins[idx & (GG - 1)] == sins[gn];
    bool matched = ex && same;
    res = matched ? sbest[gn] : -1;
    bool stop = matched || (!same) || (steps >= GG + 2);
    idx = gnr;
    ++steps;
    if (stop) break;
  }
  ws->next_pred[b * NN + i] = res;
  if (res >= 0) {
    atomicAdd(&ws->col_cnt[b * NN + res], 1);
    const float* pb = positions + (size_t)b * NN * 2;
    float d = pdist(posx(pb[2 * i]), posy(pb[2 * i + 1]),
                    posx(pb[2 * res]), posy(pb[2 * res + 1]));
    atomicMin(&ws->keep_key[b * NN + res], pack_key(d, i));
  }
}

// write the 1-entries of A (out already zeroed)
__global__ __launch_bounds__(256) void k_scatter(Ws* ws, float* __restrict__ out) {
  const int bpb = NN / 256;
  int b = blockIdx.x / bpb;
  int i = (blockIdx.x % bpb) * 256 + threadIdx.x;

  float* A = out + 3 + (size_t)b * MM * MM;

  int j = ws->next_pred[b * NN + i];
  bool surv = (j >= 0) && ((int)(ws->keep_key[b * NN + j] & 0xFFFFFFFFULL) == i);
  if (surv) A[(size_t)i * MM + j] = 1.0f;          // row i keeps its match
  else      A[(size_t)i * MM + (MM - 1)] = 1.0f;   // row fix: dustbin column

  if (ws->col_cnt[b * NN + i] == 0)                // i as column index
    A[(size_t)(MM - 1) * MM + i] = 1.0f;           // col fix: dustbin row
}

// loss gathers + per-batch sums (tgt_f / tgt_b derived analytically)
__global__ __launch_bounds__(256) void k_loss(const float* __restrict__ matches, Ws* ws) {
  __shared__ float sred[4];
  const int bpb = NN / 256;
  int b = blockIdx.x / bpb;
  int k = (blockIdx.x % bpb) * 256 + threadIdx.x;

  int j = ws->next_pred[b * NN + k];
  bool surv = (j >= 0) && ((int)(ws->keep_key[b * NN + j] & 0xFFFFFFFFULL) == k);
  int tf = surv ? j : (MM - 1);
  float vf = matches[(size_t)b * MM * MM + (size_t)k * MM + tf];

  int cnt = ws->col_cnt[b * NN + k];
  int tb = (cnt > 0) ? (int)(ws->keep_key[b * NN + k] & 0xFFFFFFFFULL) : (MM - 1);
  float vb = matches[(size_t)b * MM * MM + (size_t)k * MM + tb];

  int lane = threadIdx.x & 63, w = threadIdx.x >> 6;

  float v = vf;
  #pragma unroll
  for (int o = 32; o > 0; o >>= 1) v += __shfl_down(v, o, 64);
  if (lane == 0) sred[w] = v;
  __syncthreads();
  if (threadIdx.x == 0) atomicAdd(&ws->lossf_sum[b], sred[0] + sred[1] + sred[2] + sred[3]);
  __syncthreads();

  v = vb;
  #pragma unroll
  for (int o = 32; o > 0; o >>= 1) v += __shfl_down(v, o, 64);
  if (lane == 0) sred[w] = v;
  __syncthreads();
  if (threadIdx.x == 0) atomicAdd(&ws->lossb_sum[b], sred[0] + sred[1] + sred[2] + sred[3]);
}

__global__ void k_final(Ws* ws, float* __restrict__ out) {
  if (threadIdx.x == 0 && blockIdx.x == 0) {
    float cm = 0.f, ml = 0.f, sl = 0.f;
    for (int b = 0; b < BB; ++b) {
      cm += ws->cdist_sum[b] / (float)NN;
      float lf = -(ws->lossf_sum[b] / (float)(MM - 1));
      float lb = -(ws->lossb_sum[b] / (float)(MM - 1));
      ml += 0.5f * (lf + lb);
      sl += -(ws->sem_sum[b] / (float)NN);
    }
    out[0] = cm / (float)BB;
    out[1] = ml / (float)BB;
    out[2] = sl / (float)BB;
  }
}

// ---------------- launch ----------------
extern "C" void kernel_launch(void* const* d_in, const int* in_sizes, int n_in,
                              void* d_out, int out_size, void* d_ws, size_t ws_size,
                              hipStream_t stream) {
  (void)in_sizes; (void)n_in; (void)ws_size;
  const float* matches   = (const float*)d_in[0];
  const float* positions = (const float*)d_in[1];
  const float* semantics = (const float*)d_in[2];
  // d_in[3] = masks (unused by reference)
  const float* gt_pts    = (const float*)d_in[4];
  const int*   gt_ins    = (const int*)d_in[5];
  const int*   gt_type   = (const int*)d_in[6];
  float* out = (float*)d_out;
  Ws* ws = (Ws*)d_ws;

  k_zero<<<2048, 256, 0, stream>>>(out, out_size);
  k_init<<<(BB * NN + 255) / 256, 256, 0, stream>>>(ws);
  k_nearest<<<BB * (NN / 256), 256, 0, stream>>>(positions, gt_pts, gt_type, semantics, ws, out);
  k_walk<<<BB * (NN / 256), 256, 0, stream>>>(gt_ins, positions, ws);
  k_scatter<<<BB * (NN / 256), 256, 0, stream>>>(ws, out);
  k_loss<<<BB * (NN / 256), 256, 0, stream>>>(matches, ws);
  k_final<<<1, 64, 0, stream>>>(ws, out);
}

// Round 5
// 150.776 us; speedup vs baseline: 2.7342x; 1.1381x over previous
//
#include <hip/hip_runtime.h>
#include <math.h>

#define BB 4
#define NN 2048
#define GG 1024
#define CC 3
#define MM 2049   // NN+1
#define SP 8      // G-splits for nearest
#define CH (GG / SP)

typedef unsigned long long u64;
#define KEY_EMPTY 0xFFFFFFFFFFFFFFFFULL

// ---------------- workspace layout ----------------
struct Ws {
  u64   near_key[BB * NN];    // (bits(dmin)<<32) | g  : per-point argmin over gts
  u64   best_key[BB * GG];    // (bits(dmin)<<32) | i  : per-gt argmin over points; EMPTY => none
  u64   keep_key[BB * NN];    // (bits(dist)<<32) | i  : surviving row for column j
  int   nearest[BB * NN];
  int   next_pred[BB * NN];
  int   col_cnt[BB * NN];
  int   nmax[BB];
  float cdist_sum[BB];
  float sem_sum[BB];
  float lossf_sum[BB];
  float lossb_sum[BB];
};

// position transform + pairwise distance, bit-matching XLA's sub->mul->add->sqrt
__device__ __forceinline__ float posx(float p) { return __fadd_rn(__fmul_rn(p, 0.15f), -29.925f); }
__device__ __forceinline__ float posy(float p) { return __fadd_rn(__fmul_rn(p, 0.15f), -14.925f); }
__device__ __forceinline__ float pdist(float ax, float ay, float bx, float by) {
  float dx = __fsub_rn(ax, bx);
  float dy = __fsub_rn(ay, by);
  return __fsqrt_rn(__fadd_rn(__fmul_rn(dx, dx), __fmul_rn(dy, dy)));
}
__device__ __forceinline__ u64 pack_key(float d, int i) {
  return ((u64)__float_as_uint(d) << 32) | (unsigned int)i;
}

// ---------------- kernels ----------------

__global__ void k_init(Ws* ws) {
  int t = blockIdx.x * blockDim.x + threadIdx.x;
  if (t < BB * NN) {
    ws->near_key[t] = KEY_EMPTY;
    ws->keep_key[t] = KEY_EMPTY;
    ws->col_cnt[t] = 0;
  }
  if (t < BB * GG) ws->best_key[t] = KEY_EMPTY;
  if (t < BB) {
    ws->nmax[t] = 0;
    ws->cdist_sum[t] = 0.f;
    ws->sem_sum[t] = 0.f;
    ws->lossf_sum[t] = 0.f;
    ws->lossb_sum[t] = 0.f;
  }
}

// pass 1: per-point min over a 128-gt chunk, combined via packed atomicMin.
// key = (bits(d)<<32)|g : lexicographic min == smallest d, ties -> smallest g
// == jnp.argmin first-index tie-break.
__global__ __launch_bounds__(256) void k_near1(const float* __restrict__ positions,
                                               const float* __restrict__ gt_pts, Ws* ws) {
  __shared__ float spts[CH * 2];
  const int cpb = NN / 256;                  // point-chunks per batch
  int b = blockIdx.x / (cpb * SP);
  int r = blockIdx.x % (cpb * SP);
  int i = (r / SP) * 256 + threadIdx.x;
  int g0 = (r % SP) * CH;

  spts[threadIdx.x] = gt_pts[b * GG * 2 + g0 * 2 + threadIdx.x];  // CH*2 == 256 floats
  __syncthreads();

  float px = posx(positions[(size_t)(b * NN + i) * 2 + 0]);
  float py = posy(positions[(size_t)(b * NN + i) * 2 + 1]);

  float dmin = INFINITY;
  int gmin = 0;
  #pragma unroll 4
  for (int g = 0; g < CH; ++g) {
    float d = pdist(px, py, spts[2 * g], spts[2 * g + 1]);
    if (d < dmin) { dmin = d; gmin = g; }    // strict < : first-index within chunk
  }
  atomicMin(&ws->near_key[b * NN + i], pack_key(dmin, g0 + gmin));
}

// pass 2: unpack nearest, one-hot semantics, sem gather, best_key scatter, reductions
__global__ __launch_bounds__(64) void k_near2(const int* __restrict__ gt_type,
                                              const float* __restrict__ semantics,
                                              Ws* ws, float* __restrict__ out) {
  int b = blockIdx.x >> 5;                   // 32 blocks of 64 per batch
  int i = (blockIdx.x & 31) * 64 + threadIdx.x;

  u64 key = ws->near_key[b * NN + i];
  float dmin = __uint_as_float((unsigned int)(key >> 32));
  int g = (int)(key & 0xFFFFFFFFULL);

  ws->nearest[b * NN + i] = g;
  atomicMin(&ws->best_key[b * GG + g], pack_key(dmin, i));   // cd[i,nearest[i]] == dmin

  int cls = gt_type[b * GG + g];
  float* sg = out + 3 + (size_t)BB * MM * MM;
  sg[(size_t)b * CC * NN + 0 * NN + i] = (cls == 0) ? 1.f : 0.f;
  sg[(size_t)b * CC * NN + 1 * NN + i] = (cls == 1) ? 1.f : 0.f;
  sg[(size_t)b * CC * NN + 2 * NN + i] = (cls == 2) ? 1.f : 0.f;
  float sem = semantics[(size_t)b * CC * NN + (size_t)cls * NN + i];

  float v = dmin;
  #pragma unroll
  for (int o = 32; o > 0; o >>= 1) v += __shfl_down(v, o, 64);
  if (threadIdx.x == 0) atomicAdd(&ws->cdist_sum[b], v);

  v = sem;
  #pragma unroll
  for (int o = 32; o > 0; o >>= 1) v += __shfl_down(v, o, 64);
  if (threadIdx.x == 0) atomicAdd(&ws->sem_sum[b], v);

  int m = g;
  #pragma unroll
  for (int o = 32; o > 0; o >>= 1) m = max(m, __shfl_down(m, o, 64));
  if (threadIdx.x == 0) atomicMax(&ws->nmax[b], m);
}

// the jax.lax.while_loop walk + scatter-argmin for keep[]
__global__ __launch_bounds__(64) void k_walk(const int* __restrict__ gt_ins,
                                             const float* __restrict__ positions, Ws* ws) {
  __shared__ int sins[GG];
  __shared__ int sbest[GG];
  int b = blockIdx.x >> 5;
  int i = (blockIdx.x & 31) * 64 + threadIdx.x;

  // vectorized cooperative staging
  {
    const int4* src = reinterpret_cast<const int4*>(gt_ins + b * GG);
    int4* dst = reinterpret_cast<int4*>(sins);
    for (int t = threadIdx.x; t < GG / 4; t += 64) dst[t] = src[t];
    const u64* bk = ws->best_key + b * GG;
    for (int t = threadIdx.x; t < GG; t += 64) {
      u64 k = bk[t];
      sbest[t] = (k == KEY_EMPTY) ? -1 : (int)(k & 0xFFFFFFFFULL);
    }
  }
  __syncthreads();

  int nmax = ws->nmax[b];
  int idx = ws->nearest[b * NN + i];
  int steps = 0, res = -1;
  while (true) {
    bool is_end = idx >= nmax;
    int gnr = is_end ? -1 : idx + 1;
    int gn = gnr & (GG - 1);                 // jnp.mod for pow2 (handles -1 -> G-1)
    bool ex = (!is_end) && (sbest[gn] >= 0);
    bool same = sins[idx & (GG - 1)] == sins[gn];
    bool matched = ex && same;
    res = matched ? sbest[gn] : -1;
    bool stop = matched || (!same) || (steps >= GG + 2);
    idx = gnr;
    ++steps;
    if (stop) break;
  }
  ws->next_pred[b * NN + i] = res;
  if (res >= 0) {
    atomicAdd(&ws->col_cnt[b * NN + res], 1);
    const float* pb = positions + (size_t)b * NN * 2;
    float d = pdist(posx(pb[2 * i]), posy(pb[2 * i + 1]),
                    posx(pb[2 * res]), posy(pb[2 * res + 1]));
    atomicMin(&ws->keep_key[b * NN + res], pack_key(d, i));
  }
}

// fused: write the 1-entries of A (out already zeroed) + loss gathers/reductions
__global__ __launch_bounds__(64) void k_post(const float* __restrict__ matches,
                                             Ws* ws, float* __restrict__ out) {
  int b = blockIdx.x >> 5;
  int i = (blockIdx.x & 31) * 64 + threadIdx.x;

  float* A = out + 3 + (size_t)b * MM * MM;

  int j = ws->next_pred[b * NN + i];
  bool surv = (j >= 0) && ((int)(ws->keep_key[b * NN + j] & 0xFFFFFFFFULL) == i);
  if (surv) A[(size_t)i * MM + j] = 1.0f;          // row i keeps its match
  else      A[(size_t)i * MM + (MM - 1)] = 1.0f;   // row fix: dustbin column

  int cnt = ws->col_cnt[b * NN + i];               // i as column index
  if (cnt == 0) A[(size_t)(MM - 1) * MM + i] = 1.0f; // col fix: dustbin row

  // losses (tgt_f / tgt_b derived analytically)
  int tf = surv ? j : (MM - 1);
  float vf = matches[(size_t)b * MM * MM + (size_t)i * MM + tf];
  int tb = (cnt > 0) ? (int)(ws->keep_key[b * NN + i] & 0xFFFFFFFFULL) : (MM - 1);
  float vb = matches[(size_t)b * MM * MM + (size_t)i * MM + tb];

  float v = vf;
  #pragma unroll
  for (int o = 32; o > 0; o >>= 1) v += __shfl_down(v, o, 64);
  if (threadIdx.x == 0) atomicAdd(&ws->lossf_sum[b], v);

  v = vb;
  #pragma unroll
  for (int o = 32; o > 0; o >>= 1) v += __shfl_down(v, o, 64);
  if (threadIdx.x == 0) atomicAdd(&ws->lossb_sum[b], v);
}

__global__ void k_final(Ws* ws, float* __restrict__ out) {
  if (threadIdx.x == 0 && blockIdx.x == 0) {
    float cm = 0.f, ml = 0.f, sl = 0.f;
    for (int b = 0; b < BB; ++b) {
      cm += ws->cdist_sum[b] / (float)NN;
      float lf = -(ws->lossf_sum[b] / (float)(MM - 1));
      float lb = -(ws->lossb_sum[b] / (float)(MM - 1));
      ml += 0.5f * (lf + lb);
      sl += -(ws->sem_sum[b] / (float)NN);
    }
    out[0] = cm / (float)BB;
    out[1] = ml / (float)BB;
    out[2] = sl / (float)BB;
  }
}

// ---------------- launch ----------------
extern "C" void kernel_launch(void* const* d_in, const int* in_sizes, int n_in,
                              void* d_out, int out_size, void* d_ws, size_t ws_size,
                              hipStream_t stream) {
  (void)in_sizes; (void)n_in; (void)ws_size;
  const float* matches   = (const float*)d_in[0];
  const float* positions = (const float*)d_in[1];
  const float* semantics = (const float*)d_in[2];
  // d_in[3] = masks (unused by reference)
  const float* gt_pts    = (const float*)d_in[4];
  const int*   gt_ins    = (const int*)d_in[5];
  const int*   gt_type   = (const int*)d_in[6];
  float* out = (float*)d_out;
  Ws* ws = (Ws*)d_ws;

  hipMemsetAsync(d_out, 0, (size_t)out_size * sizeof(float), stream);
  k_init<<<(BB * NN + 255) / 256, 256, 0, stream>>>(ws);
  k_near1<<<BB * (NN / 256) * SP, 256, 0, stream>>>(positions, gt_pts, ws);
  k_near2<<<BB * (NN / 64), 64, 0, stream>>>(gt_type, semantics, ws, out);
  k_walk<<<BB * (NN / 64), 64, 0, stream>>>(gt_ins, positions, ws);
  k_post<<<BB * (NN / 64), 64, 0, stream>>>(matches, ws, out);
  k_final<<<1, 64, 0, stream>>>(ws, out);
}